// Round 1
// baseline (1306.798 us; speedup 1.0000x reference)
//
#include <hip/hip_runtime.h>
#include <stdint.h>

#define HIDDEN 4096
#define M_TOK 8192   // B*S
#define KDIM 4096

typedef __attribute__((ext_vector_type(8))) __bf16 bf16x8;
typedef __attribute__((ext_vector_type(4))) float f32x4;
typedef __attribute__((ext_vector_type(8))) unsigned short u16x8;

#define GAS __attribute__((address_space(1)))
#define LAS __attribute__((address_space(3)))

__device__ __forceinline__ unsigned short f2bf(float f) {
  unsigned int u = __float_as_uint(f);
  u += 0x7FFFu + ((u >> 16) & 1u);
  return (unsigned short)(u >> 16);
}
__device__ __forceinline__ float bf2f(unsigned short b) {
  return __uint_as_float(((unsigned int)b) << 16);
}

// ---------- fp32 -> bf16, 8 elems/thread ----------
__global__ __launch_bounds__(256) void cvt_kernel(const float* __restrict__ in,
                                                  unsigned short* __restrict__ out,
                                                  int n8) {
  int i = blockIdx.x * 256 + threadIdx.x;
  if (i >= n8) return;
  const f32x4* p = (const f32x4*)in + (size_t)2 * i;
  f32x4 a = p[0], b = p[1];
  u16x8 o;
  o[0] = f2bf(a.x); o[1] = f2bf(a.y); o[2] = f2bf(a.z); o[3] = f2bf(a.w);
  o[4] = f2bf(b.x); o[5] = f2bf(b.y); o[6] = f2bf(b.z); o[7] = f2bf(b.w);
  ((u16x8*)out)[i] = o;
}

// ---------- fused QKV GEMM: out[n_mat][m][c] = sum_k A[m][k]*W[n][k] + bias[n] ----------
// m97 structure: 128x128 tile, BK=32, 4 waves (2x2), 4x4 16x16x32 frags/wave,
// global_load_lds width 16, 2 barriers per K-step.
#define BK 32

__global__ __launch_bounds__(256) void gemm_qkv(
    const unsigned short* __restrict__ A,   // [8192][4096] bf16
    const unsigned short* __restrict__ W,   // [12288][4096] bf16 (wq;wk;wv rows)
    const float* __restrict__ bias,         // [12288]
    unsigned short* __restrict__ out) {     // [3][8192][4096] bf16
  __shared__ unsigned short As[128 * BK];
  __shared__ unsigned short Bs[128 * BK];

  int bid = blockIdx.x;
  // XCD-aware bijective swizzle (gridDim.x = 6144, divisible by 8)
  int wg = (bid & 7) * (gridDim.x >> 3) + (bid >> 3);
  int tm = wg / 96;
  int tn = wg - tm * 96;
  int m0 = tm << 7, n0 = tn << 7;

  int tid = threadIdx.x;
  int lane = tid & 63;
  int wave = tid >> 6;
  int wm = (wave >> 1) << 6;
  int wn = (wave & 1) << 6;
  int l16 = lane & 15;
  int lk = lane >> 4;

  // staging: thread t covers tile row t>>2, cols (t&3)*8 (8 bf16 = 16B)
  const unsigned short* a0 = A + (size_t)(m0 + (tid >> 2)) * KDIM + (tid & 3) * 8;
  const unsigned short* a1 = a0 + (size_t)64 * KDIM;
  const unsigned short* b0 = W + (size_t)(n0 + (tid >> 2)) * KDIM + (tid & 3) * 8;
  const unsigned short* b1 = b0 + (size_t)64 * KDIM;
  unsigned short* ad0 = As + tid * 8;
  unsigned short* ad1 = As + 2048 + tid * 8;
  unsigned short* bd0 = Bs + tid * 8;
  unsigned short* bd1 = Bs + 2048 + tid * 8;

  int aoff[4], boff[4];
#pragma unroll
  for (int i = 0; i < 4; ++i) {
    aoff[i] = (wm + i * 16 + l16) * BK + lk * 8;
    boff[i] = (wn + i * 16 + l16) * BK + lk * 8;
  }

  f32x4 acc[4][4] = {};

  for (int kt = 0; kt < KDIM; kt += BK) {
    __builtin_amdgcn_global_load_lds((GAS void*)(a0 + kt), (LAS void*)ad0, 16, 0, 0);
    __builtin_amdgcn_global_load_lds((GAS void*)(a1 + kt), (LAS void*)ad1, 16, 0, 0);
    __builtin_amdgcn_global_load_lds((GAS void*)(b0 + kt), (LAS void*)bd0, 16, 0, 0);
    __builtin_amdgcn_global_load_lds((GAS void*)(b1 + kt), (LAS void*)bd1, 16, 0, 0);
    __syncthreads();
    bf16x8 av[4], bv[4];
#pragma unroll
    for (int i = 0; i < 4; ++i) {
      av[i] = *(const bf16x8*)(As + aoff[i]);
      bv[i] = *(const bf16x8*)(Bs + boff[i]);
    }
#pragma unroll
    for (int mi = 0; mi < 4; ++mi)
#pragma unroll
      for (int nj = 0; nj < 4; ++nj)
        acc[mi][nj] = __builtin_amdgcn_mfma_f32_16x16x32_bf16(av[mi], bv[nj], acc[mi][nj], 0, 0, 0);
    __syncthreads();
  }

  // epilogue: C[row][col]: col = lane&15 (+16*nj), row = (lane>>4)*4 + r (+16*mi)
  int mat = n0 >> 12;
  int nc0 = (n0 & 4095) + wn;
  unsigned short* O = out + (size_t)mat * M_TOK * HIDDEN;
  float bb[4];
#pragma unroll
  for (int nj = 0; nj < 4; ++nj) bb[nj] = bias[n0 + wn + nj * 16 + l16];
#pragma unroll
  for (int mi = 0; mi < 4; ++mi) {
#pragma unroll
    for (int r = 0; r < 4; ++r) {
      int row = m0 + wm + mi * 16 + lk * 4 + r;
      size_t rb = (size_t)row * HIDDEN + nc0 + l16;
#pragma unroll
      for (int nj = 0; nj < 4; ++nj)
        O[rb + nj * 16] = f2bf(acc[mi][nj][r] + bb[nj]);
    }
  }
}

// ---------- per-token 32x32 head attention ----------
// block = 256 threads = 1 token. q,k,v = [32 heads][128 dim] rows of QKV.
__global__ __launch_bounds__(256) void attn_kernel(const unsigned short* __restrict__ qkv,
                                                   float* __restrict__ out) {
  __shared__ float sQ[32 * 132];  // pad 132 keeps all rows 16B-aligned
  __shared__ float sK[32 * 132];
  __shared__ float sV[32 * 132];
  __shared__ float sP[32 * 33];

  int m = blockIdx.x;
  int tid = threadIdx.x;
  const unsigned short* gq = qkv + (size_t)m * HIDDEN;
  const unsigned short* gk = gq + (size_t)M_TOK * HIDDEN;
  const unsigned short* gv = gk + (size_t)M_TOK * HIDDEN;

  int row = tid >> 3;
  int cb = (tid & 7) << 4;
  int go = row * 128 + cb;
  int lo = row * 132 + cb;
  {
    u16x8 x0 = *(const u16x8*)(gq + go);
    u16x8 x1 = *(const u16x8*)(gq + go + 8);
#pragma unroll
    for (int j = 0; j < 8; ++j) { sQ[lo + j] = bf2f(x0[j]); sQ[lo + 8 + j] = bf2f(x1[j]); }
    x0 = *(const u16x8*)(gk + go);
    x1 = *(const u16x8*)(gk + go + 8);
#pragma unroll
    for (int j = 0; j < 8; ++j) { sK[lo + j] = bf2f(x0[j]); sK[lo + 8 + j] = bf2f(x1[j]); }
    x0 = *(const u16x8*)(gv + go);
    x1 = *(const u16x8*)(gv + go + 8);
#pragma unroll
    for (int j = 0; j < 8; ++j) { sV[lo + j] = bf2f(x0[j]); sV[lo + 8 + j] = bf2f(x1[j]); }
  }
  __syncthreads();

  // scores: thread = (h = tid>>3, t4 = (tid&7)*4): 4 dots of length 128
  int h = tid >> 3;
  int t4 = (tid & 7) << 2;
  const f32x4* qr = (const f32x4*)(sQ + h * 132);
  const f32x4* k0 = (const f32x4*)(sK + (t4 + 0) * 132);
  const f32x4* k1 = (const f32x4*)(sK + (t4 + 1) * 132);
  const f32x4* k2 = (const f32x4*)(sK + (t4 + 2) * 132);
  const f32x4* k3 = (const f32x4*)(sK + (t4 + 3) * 132);
  float s0 = 0.f, s1 = 0.f, s2 = 0.f, s3 = 0.f;
#pragma unroll
  for (int d = 0; d < 32; ++d) {
    f32x4 q = qr[d];
    f32x4 a = k0[d]; s0 += q.x * a.x + q.y * a.y + q.z * a.z + q.w * a.w;
    f32x4 b = k1[d]; s1 += q.x * b.x + q.y * b.y + q.z * b.z + q.w * b.w;
    f32x4 c = k2[d]; s2 += q.x * c.x + q.y * c.y + q.z * c.z + q.w * c.w;
    f32x4 e = k3[d]; s3 += q.x * e.x + q.y * e.y + q.z * e.z + q.w * e.w;
  }
  const float scale = 0.08838834764831845f;  // 1/sqrt(128)
  s0 *= scale; s1 *= scale; s2 *= scale; s3 *= scale;
  // softmax over t: 8-lane group (same h) holds all 32 t's
  float mx = fmaxf(fmaxf(s0, s1), fmaxf(s2, s3));
  mx = fmaxf(mx, __shfl_xor(mx, 1));
  mx = fmaxf(mx, __shfl_xor(mx, 2));
  mx = fmaxf(mx, __shfl_xor(mx, 4));
  float e0 = __expf(s0 - mx), e1 = __expf(s1 - mx), e2 = __expf(s2 - mx), e3 = __expf(s3 - mx);
  float sum = e0 + e1 + e2 + e3;
  sum += __shfl_xor(sum, 1);
  sum += __shfl_xor(sum, 2);
  sum += __shfl_xor(sum, 4);
  float inv = 1.0f / sum;
  sP[h * 33 + t4 + 0] = e0 * inv;
  sP[h * 33 + t4 + 1] = e1 * inv;
  sP[h * 33 + t4 + 2] = e2 * inv;
  sP[h * 33 + t4 + 3] = e3 * inv;
  __syncthreads();

  // PV: thread = (h, d0 = (tid&7)*16): 16 output dims
  int d0 = (tid & 7) << 4;
  f32x4 o0 = {0.f, 0.f, 0.f, 0.f}, o1 = o0, o2 = o0, o3 = o0;
  const float* pr = sP + h * 33;
#pragma unroll
  for (int t = 0; t < 32; ++t) {
    float p = pr[t];
    const f32x4* vr = (const f32x4*)(sV + t * 132 + d0);
    o0 += p * vr[0];
    o1 += p * vr[1];
    o2 += p * vr[2];
    o3 += p * vr[3];
  }
  f32x4* op = (f32x4*)(out + (size_t)m * HIDDEN + h * 128 + d0);
  op[0] = o0; op[1] = o1; op[2] = o2; op[3] = o3;
}

extern "C" void kernel_launch(void* const* d_in, const int* in_sizes, int n_in,
                              void* d_out, int out_size, void* d_ws, size_t ws_size,
                              hipStream_t stream) {
  const float* hs = (const float*)d_in[0];
  const float* wq = (const float*)d_in[1];
  const float* bq = (const float*)d_in[2];
  const float* wk = (const float*)d_in[3];
  const float* bk = (const float*)d_in[4];
  const float* wv = (const float*)d_in[5];
  const float* bv = (const float*)d_in[6];
  // d_in[7] (wl), d_in[8] (bl): latent projection is unused by the output — skipped.

  char* ws = (char*)d_ws;
  const size_t HS_OFF = 0;                    // 8192*4096*2       = 64 MiB
  const size_t W_OFF = 67108864;              // 12288*4096*2      = 96 MiB
  const size_t QKV_OFF = 167772160;           // 3*8192*4096*2     = 192 MiB
  const size_t BIAS_OFF = 369098752;          // 12288*4           = 48 KiB
  const size_t NEED = 369147904;
  if (ws_size < NEED) return;  // workspace too small -> fail loudly (wrong output)

  unsigned short* hsb = (unsigned short*)(ws + HS_OFF);
  unsigned short* wb = (unsigned short*)(ws + W_OFF);
  unsigned short* qkv = (unsigned short*)(ws + QKV_OFF);
  float* bias = (float*)(ws + BIAS_OFF);

  cvt_kernel<<<16384, 256, 0, stream>>>(hs, hsb, 4194304);                 // 33.5M elems
  cvt_kernel<<<8192, 256, 0, stream>>>(wq, wb, 2097152);                   // 16.8M each
  cvt_kernel<<<8192, 256, 0, stream>>>(wk, wb + 16777216, 2097152);
  cvt_kernel<<<8192, 256, 0, stream>>>(wv, wb + 33554432, 2097152);
  hipMemcpyAsync(bias, bq, 16384, hipMemcpyDeviceToDevice, stream);
  hipMemcpyAsync(bias + 4096, bk, 16384, hipMemcpyDeviceToDevice, stream);
  hipMemcpyAsync(bias + 8192, bv, 16384, hipMemcpyDeviceToDevice, stream);

  gemm_qkv<<<6144, 256, 0, stream>>>(hsb, wb, bias, qkv);                  // 64 x 96 tiles
  attn_kernel<<<8192, 256, 0, stream>>>(qkv, (float*)d_out);               // 1 block/token
}

// Round 2
// 938.724 us; speedup vs baseline: 1.3921x; 1.3921x over previous
//
#include <hip/hip_runtime.h>
#include <stdint.h>

#define HIDDEN 4096
#define M_TOK 8192   // B*S
#define KDIM 4096

typedef __attribute__((ext_vector_type(8))) __bf16 bf16x8;
typedef __attribute__((ext_vector_type(4))) float f32x4;
typedef __attribute__((ext_vector_type(8))) unsigned short u16x8;

#define GAS __attribute__((address_space(1)))
#define LAS __attribute__((address_space(3)))

__device__ __forceinline__ unsigned short f2bf(float f) {
  unsigned int u = __float_as_uint(f);
  u += 0x7FFFu + ((u >> 16) & 1u);
  return (unsigned short)(u >> 16);
}
__device__ __forceinline__ float bf2f(unsigned short b) {
  return __uint_as_float(((unsigned int)b) << 16);
}

// ---------- fp32 -> bf16, 8 elems/thread ----------
__global__ __launch_bounds__(256) void cvt_kernel(const float* __restrict__ in,
                                                  unsigned short* __restrict__ out,
                                                  int n8) {
  int i = blockIdx.x * 256 + threadIdx.x;
  if (i >= n8) return;
  const f32x4* p = (const f32x4*)in + (size_t)2 * i;
  f32x4 a = p[0], b = p[1];
  u16x8 o;
  o[0] = f2bf(a.x); o[1] = f2bf(a.y); o[2] = f2bf(a.z); o[3] = f2bf(a.w);
  o[4] = f2bf(b.x); o[5] = f2bf(b.y); o[6] = f2bf(b.z); o[7] = f2bf(b.w);
  ((u16x8*)out)[i] = o;
}

// ============================================================================
// 256x256 8-phase QKV GEMM (m201 template, plain HIP)
// BM=BN=256, BK=64, 512 thr = 8 waves (2M x 4N), per-wave out 128x64.
// LDS 128 KiB: A[2 buf][2 half][128][64] + B likewise. st_16x32 XOR swizzle
// applied via pre-swizzled GLOBAL source (linear gload_lds dest) + swizzled
// ds_read address. Staging order per K-tile: [B0,B1,A0,A1] at phases p+2..p+5
// relative to that K-tile's 4 compute phases; reads 12/8/4/0 so each half is
// fully read (lgkmcnt(0)+barrier) before its overwrite is issued. vmcnt(6)
// at phases 4 and 8 only.
// ============================================================================
#define BAR() __builtin_amdgcn_s_barrier()
#define PRIO(p) __builtin_amdgcn_s_setprio(p)
#define VMC6() asm volatile("s_waitcnt vmcnt(6)" ::: "memory")
#define VMC4() asm volatile("s_waitcnt vmcnt(4)" ::: "memory")
#define VMC0() asm volatile("s_waitcnt vmcnt(0)" ::: "memory")
#define PH_MID() do { __builtin_amdgcn_s_barrier(); \
  asm volatile("s_waitcnt lgkmcnt(0)" ::: "memory"); \
  __builtin_amdgcn_sched_barrier(0); } while (0)

__global__ __launch_bounds__(512, 2) void gemm_qkv(
    const unsigned short* __restrict__ A,   // [8192][4096] bf16
    const unsigned short* __restrict__ W,   // [12288][4096] bf16 (wq;wk;wv)
    const float* __restrict__ bias,         // [12288]
    unsigned short* __restrict__ out) {     // [3][8192][4096] bf16
  __shared__ __attribute__((aligned(16))) unsigned short lds[65536];  // 128 KiB

  int tid = threadIdx.x;
  int lane = tid & 63;
  int w = tid >> 6;
  int wm = w >> 2;        // 0..1 -> rows wm*128
  int wn = w & 3;         // 0..3 -> cols wn*64
  int l16 = lane & 15;
  int lk = lane >> 4;

  // tile mapping with XCD swizzle (1536 blocks % 8 == 0)
  int bid = blockIdx.x;
  int wg = (bid & 7) * 192 + (bid >> 3);
  int tm = wg / 48;
  int tn = wg - tm * 48;
  int m0 = tm << 8, n0 = tn << 8;

  // ---- staging source (pre-swizzled global col so linear LDS == swizzled) ----
  int rp = tid >> 3;                                     // 0..63 row within chunk
  int ce = ((tid & 7) << 3) ^ (((tid >> 5) & 1) << 4);   // col elems, st_16x32
  const unsigned short* aSrc = A + (size_t)(m0 + rp) * KDIM + ce;
  const unsigned short* bSrc = W + (size_t)(n0 + rp) * KDIM + ce;
  int tid8 = tid * 8;  // LDS shorts offset for this thread's 16B

#define STA(b, h, kt) do { \
  __builtin_amdgcn_global_load_lds((GAS void*)(aSrc + (size_t)((h)*128) * KDIM + (kt)*64), \
      (LAS void*)(lds + (b)*16384 + (h)*8192 + tid8), 16, 0, 0); \
  __builtin_amdgcn_global_load_lds((GAS void*)(aSrc + (size_t)((h)*128 + 64) * KDIM + (kt)*64), \
      (LAS void*)(lds + (b)*16384 + (h)*8192 + 4096 + tid8), 16, 0, 0); } while (0)
#define STB(b, h, kt) do { \
  __builtin_amdgcn_global_load_lds((GAS void*)(bSrc + (size_t)((h)*128) * KDIM + (kt)*64), \
      (LAS void*)(lds + 32768 + (b)*16384 + (h)*8192 + tid8), 16, 0, 0); \
  __builtin_amdgcn_global_load_lds((GAS void*)(bSrc + (size_t)((h)*128 + 64) * KDIM + (kt)*64), \
      (LAS void*)(lds + 32768 + (b)*16384 + (h)*8192 + 4096 + tid8), 16, 0, 0); } while (0)

  // ---- fragment read addressing (swizzled): swz bit depends only on l16 ----
  int colbase = (lk << 3) ^ (((l16 >> 2) & 1) << 4);     // shorts
  int aRd = wm * 8192 + l16 * 64 + colbase;
  int bRd = (wn >> 1) * 8192 + (wn & 1) * 4096 + l16 * 64 + colbase;

#define RD_A(c, mi, ks) (*(const bf16x8*)(lds + (c)*16384 + aRd + (mi)*1024 + (ks)*32))
#define RD_B(c, nj, ks) (*(const bf16x8*)(lds + 32768 + (c)*16384 + bRd + (nj)*1024 + (ks)*32))

  bf16x8 av[8][2];
  bf16x8 bv[4][2];
  f32x4 acc[8][4] = {};

#define RP1(c) do { \
  bv[0][0]=RD_B(c,0,0); bv[0][1]=RD_B(c,0,1); bv[1][0]=RD_B(c,1,0); bv[1][1]=RD_B(c,1,1); \
  bv[2][0]=RD_B(c,2,0); bv[2][1]=RD_B(c,2,1); bv[3][0]=RD_B(c,3,0); bv[3][1]=RD_B(c,3,1); \
  av[0][0]=RD_A(c,0,0); av[0][1]=RD_A(c,0,1); av[1][0]=RD_A(c,1,0); av[1][1]=RD_A(c,1,1); } while (0)
#define RP2(c) do { \
  av[2][0]=RD_A(c,2,0); av[2][1]=RD_A(c,2,1); av[3][0]=RD_A(c,3,0); av[3][1]=RD_A(c,3,1); \
  av[4][0]=RD_A(c,4,0); av[4][1]=RD_A(c,4,1); av[5][0]=RD_A(c,5,0); av[5][1]=RD_A(c,5,1); } while (0)
#define RP3(c) do { \
  av[6][0]=RD_A(c,6,0); av[6][1]=RD_A(c,6,1); av[7][0]=RD_A(c,7,0); av[7][1]=RD_A(c,7,1); } while (0)

#define MFMA2(mi, nj) do { \
  acc[mi][nj] = __builtin_amdgcn_mfma_f32_16x16x32_bf16(av[mi][0], bv[nj][0], acc[mi][nj], 0, 0, 0); \
  acc[mi][nj] = __builtin_amdgcn_mfma_f32_16x16x32_bf16(av[mi][1], bv[nj][1], acc[mi][nj], 0, 0, 0); } while (0)
#define MM(mi) do { MFMA2(mi,0); MFMA2(mi,1); MFMA2(mi,2); MFMA2(mi,3); } while (0)

  // ---- prologue: kt0 full (B0,B1,A0,A1) + kt1 (B0,B1,A0); 6 loads in flight ----
  STB(0, 0, 0); STB(0, 1, 0); STA(0, 0, 0); STA(0, 1, 0);
  VMC4();
  STB(1, 0, 1); STB(1, 1, 1); STA(1, 0, 1);
  VMC6();
  BAR();

  // ---- main loop: 31 iters x 2 K-tiles; epilogue iter drains kt62/kt63 ----
  for (int it = 0; it < 31; ++it) {
    int k1 = 2 * it + 1, k2 = 2 * it + 2, k3 = 2 * it + 3;
    // K-tile 2it from buf0
    RP1(0); STA(1, 1, k1); PH_MID(); PRIO(1); MM(0); MM(1); PRIO(0); BAR();
    RP2(0); STB(0, 0, k2); PH_MID(); PRIO(1); MM(2); MM(3); PRIO(0); BAR();
    RP3(0); STB(0, 1, k2); PH_MID(); PRIO(1); MM(4); MM(5); PRIO(0); BAR();
            STA(0, 0, k2); PH_MID(); PRIO(1); MM(6); MM(7); PRIO(0); VMC6(); BAR();
    // K-tile 2it+1 from buf1
    RP1(1); STA(0, 1, k2); PH_MID(); PRIO(1); MM(0); MM(1); PRIO(0); BAR();
    RP2(1); STB(1, 0, k3); PH_MID(); PRIO(1); MM(2); MM(3); PRIO(0); BAR();
    RP3(1); STB(1, 1, k3); PH_MID(); PRIO(1); MM(4); MM(5); PRIO(0); BAR();
            STA(1, 0, k3); PH_MID(); PRIO(1); MM(6); MM(7); PRIO(0); VMC6(); BAR();
  }
  // epilogue: kt62 (buf0) + kt63 (buf1), stage only A1 of kt63, drain vmcnt
  RP1(0); STA(1, 1, 63); PH_MID(); PRIO(1); MM(0); MM(1); PRIO(0); BAR();
  RP2(0);                PH_MID(); PRIO(1); MM(2); MM(3); PRIO(0); BAR();
  RP3(0);                PH_MID(); PRIO(1); MM(4); MM(5); PRIO(0); BAR();
                         PH_MID(); PRIO(1); MM(6); MM(7); PRIO(0); VMC0(); BAR();
  RP1(1);                PH_MID(); PRIO(1); MM(0); MM(1); PRIO(0); BAR();
  RP2(1);                PH_MID(); PRIO(1); MM(2); MM(3); PRIO(0); BAR();
  RP3(1);                PH_MID(); PRIO(1); MM(4); MM(5); PRIO(0); BAR();
                         PH_MID(); PRIO(1); MM(6); MM(7); PRIO(0);

  // ---- C write: col = l16 + 16*nj (+ wn*64), row = lk*4 + r + 16*mi (+ wm*128) ----
  int matc = n0 >> 12;
  int ncol = (n0 & 4095) + wn * 64;
  unsigned short* O = out + (size_t)matc * M_TOK * HIDDEN;
  float bb[4];
#pragma unroll
  for (int nj = 0; nj < 4; ++nj) bb[nj] = bias[n0 + wn * 64 + nj * 16 + l16];
#pragma unroll
  for (int mi = 0; mi < 8; ++mi) {
#pragma unroll
    for (int r = 0; r < 4; ++r) {
      int row = m0 + wm * 128 + mi * 16 + lk * 4 + r;
      size_t rb = (size_t)row * HIDDEN + ncol + l16;
#pragma unroll
      for (int nj = 0; nj < 4; ++nj)
        O[rb + nj * 16] = f2bf(acc[mi][nj][r] + bb[nj]);
    }
  }
}

// ---------- per-token 32x32 head attention ----------
__global__ __launch_bounds__(256) void attn_kernel(const unsigned short* __restrict__ qkv,
                                                   float* __restrict__ out) {
  __shared__ float sQ[32 * 132];
  __shared__ float sK[32 * 132];
  __shared__ float sV[32 * 132];
  __shared__ float sP[32 * 33];

  int m = blockIdx.x;
  int tid = threadIdx.x;
  const unsigned short* gq = qkv + (size_t)m * HIDDEN;
  const unsigned short* gk = gq + (size_t)M_TOK * HIDDEN;
  const unsigned short* gv = gk + (size_t)M_TOK * HIDDEN;

  int row = tid >> 3;
  int cb = (tid & 7) << 4;
  int go = row * 128 + cb;
  int lo = row * 132 + cb;
  {
    u16x8 x0 = *(const u16x8*)(gq + go);
    u16x8 x1 = *(const u16x8*)(gq + go + 8);
#pragma unroll
    for (int j = 0; j < 8; ++j) { sQ[lo + j] = bf2f(x0[j]); sQ[lo + 8 + j] = bf2f(x1[j]); }
    x0 = *(const u16x8*)(gk + go);
    x1 = *(const u16x8*)(gk + go + 8);
#pragma unroll
    for (int j = 0; j < 8; ++j) { sK[lo + j] = bf2f(x0[j]); sK[lo + 8 + j] = bf2f(x1[j]); }
    x0 = *(const u16x8*)(gv + go);
    x1 = *(const u16x8*)(gv + go + 8);
#pragma unroll
    for (int j = 0; j < 8; ++j) { sV[lo + j] = bf2f(x0[j]); sV[lo + 8 + j] = bf2f(x1[j]); }
  }
  __syncthreads();

  int h = tid >> 3;
  int t4 = (tid & 7) << 2;
  const f32x4* qr = (const f32x4*)(sQ + h * 132);
  const f32x4* k0 = (const f32x4*)(sK + (t4 + 0) * 132);
  const f32x4* k1 = (const f32x4*)(sK + (t4 + 1) * 132);
  const f32x4* k2 = (const f32x4*)(sK + (t4 + 2) * 132);
  const f32x4* k3 = (const f32x4*)(sK + (t4 + 3) * 132);
  float s0 = 0.f, s1 = 0.f, s2 = 0.f, s3 = 0.f;
#pragma unroll
  for (int d = 0; d < 32; ++d) {
    f32x4 q = qr[d];
    f32x4 a = k0[d]; s0 += q.x * a.x + q.y * a.y + q.z * a.z + q.w * a.w;
    f32x4 b = k1[d]; s1 += q.x * b.x + q.y * b.y + q.z * b.z + q.w * b.w;
    f32x4 c = k2[d]; s2 += q.x * c.x + q.y * c.y + q.z * c.z + q.w * c.w;
    f32x4 e = k3[d]; s3 += q.x * e.x + q.y * e.y + q.z * e.z + q.w * e.w;
  }
  const float scale = 0.08838834764831845f;  // 1/sqrt(128)
  s0 *= scale; s1 *= scale; s2 *= scale; s3 *= scale;
  float mx = fmaxf(fmaxf(s0, s1), fmaxf(s2, s3));
  mx = fmaxf(mx, __shfl_xor(mx, 1));
  mx = fmaxf(mx, __shfl_xor(mx, 2));
  mx = fmaxf(mx, __shfl_xor(mx, 4));
  float e0 = __expf(s0 - mx), e1 = __expf(s1 - mx), e2 = __expf(s2 - mx), e3 = __expf(s3 - mx);
  float sum = e0 + e1 + e2 + e3;
  sum += __shfl_xor(sum, 1);
  sum += __shfl_xor(sum, 2);
  sum += __shfl_xor(sum, 4);
  float inv = 1.0f / sum;
  sP[h * 33 + t4 + 0] = e0 * inv;
  sP[h * 33 + t4 + 1] = e1 * inv;
  sP[h * 33 + t4 + 2] = e2 * inv;
  sP[h * 33 + t4 + 3] = e3 * inv;
  __syncthreads();

  int d0 = (tid & 7) << 4;
  f32x4 o0 = {0.f, 0.f, 0.f, 0.f}, o1 = o0, o2 = o0, o3 = o0;
  const float* pr = sP + h * 33;
#pragma unroll
  for (int t = 0; t < 32; ++t) {
    float p = pr[t];
    const f32x4* vr = (const f32x4*)(sV + t * 132 + d0);
    o0 += p * vr[0];
    o1 += p * vr[1];
    o2 += p * vr[2];
    o3 += p * vr[3];
  }
  f32x4* op = (f32x4*)(out + (size_t)m * HIDDEN + h * 128 + d0);
  op[0] = o0; op[1] = o1; op[2] = o2; op[3] = o3;
}

extern "C" void kernel_launch(void* const* d_in, const int* in_sizes, int n_in,
                              void* d_out, int out_size, void* d_ws, size_t ws_size,
                              hipStream_t stream) {
  const float* hs = (const float*)d_in[0];
  const float* wq = (const float*)d_in[1];
  const float* bq = (const float*)d_in[2];
  const float* wk = (const float*)d_in[3];
  const float* bk = (const float*)d_in[4];
  const float* wv = (const float*)d_in[5];
  const float* bv = (const float*)d_in[6];
  // wl/bl latent projection: unused by output — skipped.

  char* ws = (char*)d_ws;
  const size_t HS_OFF = 0;                    // 64 MiB
  const size_t W_OFF = 67108864;              // 96 MiB
  const size_t QKV_OFF = 167772160;           // 192 MiB
  const size_t BIAS_OFF = 369098752;          // 48 KiB
  const size_t NEED = 369147904;
  if (ws_size < NEED) return;

  unsigned short* hsb = (unsigned short*)(ws + HS_OFF);
  unsigned short* wb = (unsigned short*)(ws + W_OFF);
  unsigned short* qkv = (unsigned short*)(ws + QKV_OFF);
  float* bias = (float*)(ws + BIAS_OFF);

  cvt_kernel<<<16384, 256, 0, stream>>>(hs, hsb, 4194304);
  cvt_kernel<<<8192, 256, 0, stream>>>(wq, wb, 2097152);
  cvt_kernel<<<8192, 256, 0, stream>>>(wk, wb + 16777216, 2097152);
  cvt_kernel<<<8192, 256, 0, stream>>>(wv, wb + 33554432, 2097152);
  hipMemcpyAsync(bias, bq, 16384, hipMemcpyDeviceToDevice, stream);
  hipMemcpyAsync(bias + 4096, bk, 16384, hipMemcpyDeviceToDevice, stream);
  hipMemcpyAsync(bias + 8192, bv, 16384, hipMemcpyDeviceToDevice, stream);

  gemm_qkv<<<1536, 512, 0, stream>>>(hsb, wb, bias, qkv);   // 32 x 48 tiles
  attn_kernel<<<8192, 256, 0, stream>>>(qkv, (float*)d_out);
}

// Round 3
// 896.642 us; speedup vs baseline: 1.4574x; 1.0469x over previous
//
#include <hip/hip_runtime.h>
#include <stdint.h>

#define HIDDEN 4096
#define M_TOK 8192   // B*S
#define KDIM 4096

typedef __attribute__((ext_vector_type(8))) __bf16 bf16x8;
typedef __attribute__((ext_vector_type(4))) float f32x4;
typedef __attribute__((ext_vector_type(8))) unsigned short u16x8;

#define GAS __attribute__((address_space(1)))
#define LAS __attribute__((address_space(3)))

__device__ __forceinline__ unsigned short f2bf(float f) {
  unsigned int u = __float_as_uint(f);
  u += 0x7FFFu + ((u >> 16) & 1u);
  return (unsigned short)(u >> 16);
}
__device__ __forceinline__ float bf2f(unsigned short b) {
  return __uint_as_float(((unsigned int)b) << 16);
}

// ---------- fp32 -> bf16, 8 elems/thread ----------
__global__ __launch_bounds__(256) void cvt_kernel(const float* __restrict__ in,
                                                  unsigned short* __restrict__ out,
                                                  int n8) {
  int i = blockIdx.x * 256 + threadIdx.x;
  if (i >= n8) return;
  const f32x4* p = (const f32x4*)in + (size_t)2 * i;
  f32x4 a = p[0], b = p[1];
  u16x8 o;
  o[0] = f2bf(a.x); o[1] = f2bf(a.y); o[2] = f2bf(a.z); o[3] = f2bf(a.w);
  o[4] = f2bf(b.x); o[5] = f2bf(b.y); o[6] = f2bf(b.z); o[7] = f2bf(b.w);
  ((u16x8*)out)[i] = o;
}

// ============================================================================
// 256x256 8-phase QKV GEMM (m201 template, plain HIP)
// BM=BN=256, BK=64, 512 thr = 8 waves (2M x 4N), per-wave out 128x64.
// LDS 128 KiB: A[2 buf][2 half][128][64] + B likewise.
// Swizzle: 3-bit XOR, byte ^= (row&7)<<4 (G4 recipe), applied via
// pre-swizzled GLOBAL source (linear gload_lds dest) + the same XOR on the
// ds_read address -> each wave64 b128 read hits all 8 16B slots with exactly
// 8 lanes = zero extra bank cycles. vmcnt(6) at phases 4/8 only.
// ============================================================================
#define BAR() __builtin_amdgcn_s_barrier()
#define PRIO(p) __builtin_amdgcn_s_setprio(p)
#define VMC6() asm volatile("s_waitcnt vmcnt(6)" ::: "memory")
#define VMC4() asm volatile("s_waitcnt vmcnt(4)" ::: "memory")
#define VMC0() asm volatile("s_waitcnt vmcnt(0)" ::: "memory")
#define PH_MID() do { __builtin_amdgcn_s_barrier(); \
  asm volatile("s_waitcnt lgkmcnt(0)" ::: "memory"); \
  __builtin_amdgcn_sched_barrier(0); } while (0)

__global__ __launch_bounds__(512, 2) void gemm_qkv(
    const unsigned short* __restrict__ A,   // [8192][4096] bf16
    const unsigned short* __restrict__ W,   // [12288][4096] bf16 (wq;wk;wv)
    const float* __restrict__ bias,         // [12288]
    unsigned short* __restrict__ out) {     // [3][8192][4096] bf16
  __shared__ __attribute__((aligned(16))) unsigned short lds[65536];  // 128 KiB

  int tid = threadIdx.x;
  int lane = tid & 63;
  int w = tid >> 6;
  int wm = w >> 2;        // 0..1 -> rows wm*128
  int wn = w & 3;         // 0..3 -> cols wn*64
  int l16 = lane & 15;
  int lk = lane >> 4;

  // tile mapping with XCD swizzle (1536 blocks % 8 == 0)
  int bid = blockIdx.x;
  int wg = (bid & 7) * 192 + (bid >> 3);
  int tm = wg / 48;
  int tn = wg - tm * 48;
  int m0 = tm << 8, n0 = tn << 8;

  // ---- staging source: pre-swizzled global col (3-bit XOR by row&7) ----
  int rp = tid >> 3;                                     // 0..63 row within chunk
  int ce = ((tid & 7) << 3) ^ ((rp & 7) << 3);           // col elems, swizzled
  const unsigned short* aSrc = A + (size_t)(m0 + rp) * KDIM + ce;
  const unsigned short* bSrc = W + (size_t)(n0 + rp) * KDIM + ce;
  int tid8 = tid * 8;  // linear LDS shorts offset for this thread's 16B

#define STA(b, h, kt) do { \
  __builtin_amdgcn_global_load_lds((GAS void*)(aSrc + (size_t)((h)*128) * KDIM + (kt)*64), \
      (LAS void*)(lds + (b)*16384 + (h)*8192 + tid8), 16, 0, 0); \
  __builtin_amdgcn_global_load_lds((GAS void*)(aSrc + (size_t)((h)*128 + 64) * KDIM + (kt)*64), \
      (LAS void*)(lds + (b)*16384 + (h)*8192 + 4096 + tid8), 16, 0, 0); } while (0)
#define STB(b, h, kt) do { \
  __builtin_amdgcn_global_load_lds((GAS void*)(bSrc + (size_t)((h)*128) * KDIM + (kt)*64), \
      (LAS void*)(lds + 32768 + (b)*16384 + (h)*8192 + tid8), 16, 0, 0); \
  __builtin_amdgcn_global_load_lds((GAS void*)(bSrc + (size_t)((h)*128 + 64) * KDIM + (kt)*64), \
      (LAS void*)(lds + 32768 + (b)*16384 + (h)*8192 + 4096 + tid8), 16, 0, 0); } while (0)

  // ---- fragment read addressing: same 3-bit XOR (row&7 == l16&7 for all frags) ----
  int colbase = (lk << 3) ^ ((l16 & 7) << 3);            // shorts, ks=0
  int aRd = wm * 8192 + l16 * 64 + colbase;
  int bRd = (wn >> 1) * 8192 + (wn & 1) * 4096 + l16 * 64 + colbase;

  // ks=1 flips linear bit5 (col bit5) -- part of the XOR field
#define RD_A(c, mi, ks) (*(const bf16x8*)(lds + (c)*16384 + (((aRd) + (mi)*1024) ^ ((ks)*32))))
#define RD_B(c, nj, ks) (*(const bf16x8*)(lds + 32768 + (c)*16384 + (((bRd) + (nj)*1024) ^ ((ks)*32))))

  bf16x8 av[8][2];
  bf16x8 bv[4][2];
  f32x4 acc[8][4] = {};

#define RP1(c) do { \
  bv[0][0]=RD_B(c,0,0); bv[0][1]=RD_B(c,0,1); bv[1][0]=RD_B(c,1,0); bv[1][1]=RD_B(c,1,1); \
  bv[2][0]=RD_B(c,2,0); bv[2][1]=RD_B(c,2,1); bv[3][0]=RD_B(c,3,0); bv[3][1]=RD_B(c,3,1); \
  av[0][0]=RD_A(c,0,0); av[0][1]=RD_A(c,0,1); av[1][0]=RD_A(c,1,0); av[1][1]=RD_A(c,1,1); } while (0)
#define RP2(c) do { \
  av[2][0]=RD_A(c,2,0); av[2][1]=RD_A(c,2,1); av[3][0]=RD_A(c,3,0); av[3][1]=RD_A(c,3,1); \
  av[4][0]=RD_A(c,4,0); av[4][1]=RD_A(c,4,1); av[5][0]=RD_A(c,5,0); av[5][1]=RD_A(c,5,1); } while (0)
#define RP3(c) do { \
  av[6][0]=RD_A(c,6,0); av[6][1]=RD_A(c,6,1); av[7][0]=RD_A(c,7,0); av[7][1]=RD_A(c,7,1); } while (0)

#define MFMA2(mi, nj) do { \
  acc[mi][nj] = __builtin_amdgcn_mfma_f32_16x16x32_bf16(av[mi][0], bv[nj][0], acc[mi][nj], 0, 0, 0); \
  acc[mi][nj] = __builtin_amdgcn_mfma_f32_16x16x32_bf16(av[mi][1], bv[nj][1], acc[mi][nj], 0, 0, 0); } while (0)
#define MM(mi) do { MFMA2(mi,0); MFMA2(mi,1); MFMA2(mi,2); MFMA2(mi,3); } while (0)

  // ---- prologue: kt0 full (B0,B1,A0,A1) + kt1 (B0,B1,A0); 6 loads in flight ----
  STB(0, 0, 0); STB(0, 1, 0); STA(0, 0, 0); STA(0, 1, 0);
  VMC4();
  STB(1, 0, 1); STB(1, 1, 1); STA(1, 0, 1);
  VMC6();
  BAR();

  // ---- main loop: 31 iters x 2 K-tiles; epilogue iter drains kt62/kt63 ----
  for (int it = 0; it < 31; ++it) {
    int k1 = 2 * it + 1, k2 = 2 * it + 2, k3 = 2 * it + 3;
    // K-tile 2it from buf0
    RP1(0); STA(1, 1, k1); PH_MID(); PRIO(1); MM(0); MM(1); PRIO(0); BAR();
    RP2(0); STB(0, 0, k2); PH_MID(); PRIO(1); MM(2); MM(3); PRIO(0); BAR();
    RP3(0); STB(0, 1, k2); PH_MID(); PRIO(1); MM(4); MM(5); PRIO(0); BAR();
            STA(0, 0, k2); PH_MID(); PRIO(1); MM(6); MM(7); PRIO(0); VMC6(); BAR();
    // K-tile 2it+1 from buf1
    RP1(1); STA(0, 1, k2); PH_MID(); PRIO(1); MM(0); MM(1); PRIO(0); BAR();
    RP2(1); STB(1, 0, k3); PH_MID(); PRIO(1); MM(2); MM(3); PRIO(0); BAR();
    RP3(1); STB(1, 1, k3); PH_MID(); PRIO(1); MM(4); MM(5); PRIO(0); BAR();
            STA(1, 0, k3); PH_MID(); PRIO(1); MM(6); MM(7); PRIO(0); VMC6(); BAR();
  }
  // epilogue: kt62 (buf0) + kt63 (buf1), stage only A1 of kt63, drain vmcnt
  RP1(0); STA(1, 1, 63); PH_MID(); PRIO(1); MM(0); MM(1); PRIO(0); BAR();
  RP2(0);                PH_MID(); PRIO(1); MM(2); MM(3); PRIO(0); BAR();
  RP3(0);                PH_MID(); PRIO(1); MM(4); MM(5); PRIO(0); BAR();
                         PH_MID(); PRIO(1); MM(6); MM(7); PRIO(0); VMC0(); BAR();
  RP1(1);                PH_MID(); PRIO(1); MM(0); MM(1); PRIO(0); BAR();
  RP2(1);                PH_MID(); PRIO(1); MM(2); MM(3); PRIO(0); BAR();
  RP3(1);                PH_MID(); PRIO(1); MM(4); MM(5); PRIO(0); BAR();
                         PH_MID(); PRIO(1); MM(6); MM(7); PRIO(0);

  // ---- C write: col = l16 + 16*nj (+ wn*64), row = lk*4 + r + 16*mi (+ wm*128) ----
  int matc = n0 >> 12;
  int ncol = (n0 & 4095) + wn * 64;
  unsigned short* O = out + (size_t)matc * M_TOK * HIDDEN;
  float bb[4];
#pragma unroll
  for (int nj = 0; nj < 4; ++nj) bb[nj] = bias[n0 + wn * 64 + nj * 16 + l16];
#pragma unroll
  for (int mi = 0; mi < 8; ++mi) {
#pragma unroll
    for (int r = 0; r < 4; ++r) {
      int row = m0 + wm * 128 + mi * 16 + lk * 4 + r;
      size_t rb = (size_t)row * HIDDEN + ncol + l16;
#pragma unroll
      for (int nj = 0; nj < 4; ++nj)
        O[rb + nj * 16] = f2bf(acc[mi][nj][r] + bb[nj]);
    }
  }
}

// ---------- per-token 32x32 head attention ----------
__global__ __launch_bounds__(256) void attn_kernel(const unsigned short* __restrict__ qkv,
                                                   float* __restrict__ out) {
  __shared__ float sQ[32 * 132];
  __shared__ float sK[32 * 132];
  __shared__ float sV[32 * 132];
  __shared__ float sP[32 * 33];

  int m = blockIdx.x;
  int tid = threadIdx.x;
  const unsigned short* gq = qkv + (size_t)m * HIDDEN;
  const unsigned short* gk = gq + (size_t)M_TOK * HIDDEN;
  const unsigned short* gv = gk + (size_t)M_TOK * HIDDEN;

  int row = tid >> 3;
  int cb = (tid & 7) << 4;
  int go = row * 128 + cb;
  int lo = row * 132 + cb;
  {
    u16x8 x0 = *(const u16x8*)(gq + go);
    u16x8 x1 = *(const u16x8*)(gq + go + 8);
#pragma unroll
    for (int j = 0; j < 8; ++j) { sQ[lo + j] = bf2f(x0[j]); sQ[lo + 8 + j] = bf2f(x1[j]); }
    x0 = *(const u16x8*)(gk + go);
    x1 = *(const u16x8*)(gk + go + 8);
#pragma unroll
    for (int j = 0; j < 8; ++j) { sK[lo + j] = bf2f(x0[j]); sK[lo + 8 + j] = bf2f(x1[j]); }
    x0 = *(const u16x8*)(gv + go);
    x1 = *(const u16x8*)(gv + go + 8);
#pragma unroll
    for (int j = 0; j < 8; ++j) { sV[lo + j] = bf2f(x0[j]); sV[lo + 8 + j] = bf2f(x1[j]); }
  }
  __syncthreads();

  int h = tid >> 3;
  int t4 = (tid & 7) << 2;
  const f32x4* qr = (const f32x4*)(sQ + h * 132);
  const f32x4* k0 = (const f32x4*)(sK + (t4 + 0) * 132);
  const f32x4* k1 = (const f32x4*)(sK + (t4 + 1) * 132);
  const f32x4* k2 = (const f32x4*)(sK + (t4 + 2) * 132);
  const f32x4* k3 = (const f32x4*)(sK + (t4 + 3) * 132);
  float s0 = 0.f, s1 = 0.f, s2 = 0.f, s3 = 0.f;
#pragma unroll
  for (int d = 0; d < 32; ++d) {
    f32x4 q = qr[d];
    f32x4 a = k0[d]; s0 += q.x * a.x + q.y * a.y + q.z * a.z + q.w * a.w;
    f32x4 b = k1[d]; s1 += q.x * b.x + q.y * b.y + q.z * b.z + q.w * b.w;
    f32x4 c = k2[d]; s2 += q.x * c.x + q.y * c.y + q.z * c.z + q.w * c.w;
    f32x4 e = k3[d]; s3 += q.x * e.x + q.y * e.y + q.z * e.z + q.w * e.w;
  }
  const float scale = 0.08838834764831845f;  // 1/sqrt(128)
  s0 *= scale; s1 *= scale; s2 *= scale; s3 *= scale;
  float mx = fmaxf(fmaxf(s0, s1), fmaxf(s2, s3));
  mx = fmaxf(mx, __shfl_xor(mx, 1));
  mx = fmaxf(mx, __shfl_xor(mx, 2));
  mx = fmaxf(mx, __shfl_xor(mx, 4));
  float e0 = __expf(s0 - mx), e1 = __expf(s1 - mx), e2 = __expf(s2 - mx), e3 = __expf(s3 - mx);
  float sum = e0 + e1 + e2 + e3;
  sum += __shfl_xor(sum, 1);
  sum += __shfl_xor(sum, 2);
  sum += __shfl_xor(sum, 4);
  float inv = 1.0f / sum;
  sP[h * 33 + t4 + 0] = e0 * inv;
  sP[h * 33 + t4 + 1] = e1 * inv;
  sP[h * 33 + t4 + 2] = e2 * inv;
  sP[h * 33 + t4 + 3] = e3 * inv;
  __syncthreads();

  int d0 = (tid & 7) << 4;
  f32x4 o0 = {0.f, 0.f, 0.f, 0.f}, o1 = o0, o2 = o0, o3 = o0;
  const float* pr = sP + h * 33;
#pragma unroll
  for (int t = 0; t < 32; ++t) {
    float p = pr[t];
    const f32x4* vr = (const f32x4*)(sV + t * 132 + d0);
    o0 += p * vr[0];
    o1 += p * vr[1];
    o2 += p * vr[2];
    o3 += p * vr[3];
  }
  f32x4* op = (f32x4*)(out + (size_t)m * HIDDEN + h * 128 + d0);
  op[0] = o0; op[1] = o1; op[2] = o2; op[3] = o3;
}

extern "C" void kernel_launch(void* const* d_in, const int* in_sizes, int n_in,
                              void* d_out, int out_size, void* d_ws, size_t ws_size,
                              hipStream_t stream) {
  const float* hs = (const float*)d_in[0];
  const float* wq = (const float*)d_in[1];
  const float* bq = (const float*)d_in[2];
  const float* wk = (const float*)d_in[3];
  const float* bk = (const float*)d_in[4];
  const float* wv = (const float*)d_in[5];
  const float* bv = (const float*)d_in[6];
  // wl/bl latent projection: unused by output — skipped.

  char* ws = (char*)d_ws;
  const size_t HS_OFF = 0;                    // 64 MiB
  const size_t W_OFF = 67108864;              // 96 MiB
  const size_t QKV_OFF = 167772160;           // 192 MiB
  const size_t BIAS_OFF = 369098752;          // 48 KiB
  const size_t NEED = 369147904;
  if (ws_size < NEED) return;

  unsigned short* hsb = (unsigned short*)(ws + HS_OFF);
  unsigned short* wb = (unsigned short*)(ws + W_OFF);
  unsigned short* qkv = (unsigned short*)(ws + QKV_OFF);
  float* bias = (float*)(ws + BIAS_OFF);

  cvt_kernel<<<16384, 256, 0, stream>>>(hs, hsb, 4194304);
  cvt_kernel<<<8192, 256, 0, stream>>>(wq, wb, 2097152);
  cvt_kernel<<<8192, 256, 0, stream>>>(wk, wb + 16777216, 2097152);
  cvt_kernel<<<8192, 256, 0, stream>>>(wv, wb + 33554432, 2097152);
  hipMemcpyAsync(bias, bq, 16384, hipMemcpyDeviceToDevice, stream);
  hipMemcpyAsync(bias + 4096, bk, 16384, hipMemcpyDeviceToDevice, stream);
  hipMemcpyAsync(bias + 8192, bv, 16384, hipMemcpyDeviceToDevice, stream);

  gemm_qkv<<<1536, 512, 0, stream>>>(hsb, wb, bias, qkv);   // 32 x 48 tiles
  attn_kernel<<<8192, 256, 0, stream>>>(qkv, (float*)d_out);
}